// Round 10
// baseline (307.445 us; speedup 1.0000x reference)
//
#include <hip/hip_runtime.h>
#include <hip/hip_bf16.h>

typedef short short8 __attribute__((ext_vector_type(8)));
typedef float f32x4 __attribute__((ext_vector_type(4)));
typedef unsigned int uint4v __attribute__((ext_vector_type(4)));

__device__ __forceinline__ short f2bf(float f) {
  unsigned u = __builtin_bit_cast(unsigned, f);
  u += 0x7fffu + ((u >> 16) & 1u);          // RNE
  return (short)(u >> 16);
}
__device__ __forceinline__ float bf2f(short s) {
  unsigned u = ((unsigned)(unsigned short)s) << 16;
  return __builtin_bit_cast(float, u);
}
__device__ __forceinline__ unsigned pk2(float a, float b) {
  __hip_bfloat162 h = __float22bfloat162_rn(float2{a, b});
  unsigned u;
  __builtin_memcpy(&u, &h, 4);
  return u;
}
__device__ __forceinline__ void gl_lds16(const void* g, void* l) {
  __builtin_amdgcn_global_load_lds(
      (const __attribute__((address_space(1))) unsigned int*)g,
      (__attribute__((address_space(3))) unsigned int*)l, 16, 0, 0);
}

// ---------------- W transpose + bf16: Wt[z][n][k], z=0:WK z=1:WV ------------
__global__ __launch_bounds__(256) void wt_kernel(
    const float* __restrict__ WK, const float* __restrict__ WV,
    short* __restrict__ Wt)
{
  const int z = blockIdx.z;
  const float* W = (z == 0) ? WK : WV;
  short* o = Wt + (size_t)z * 512 * 512;
  __shared__ short t[64][65];
  const int k0 = blockIdx.y * 64, n0 = blockIdx.x * 64;
  const int c = threadIdx.x & 63, rb = threadIdx.x >> 6;
#pragma unroll
  for (int p = 0; p < 16; ++p) {
    const int kk = p * 4 + rb;
    t[kk][c] = f2bf(W[(size_t)(k0 + kk) * 512 + n0 + c]);
  }
  __syncthreads();
#pragma unroll
  for (int p = 0; p < 16; ++p) {
    const int nn = p * 4 + rb;
    o[(size_t)(n0 + nn) * 512 + k0 + c] = t[c][nn];
  }
}

// ==== shared macros for the B-panel-resident GEMM ===========================
#define LDA(S, A0, A1, A2, A3) do { \
    const int mt_ = (S) >> 4, tt_ = (S) & 15; \
    const f32x4* ap_ = (const f32x4*)(abase + (size_t)(mt_ * 128 + ar) * 512 + tt_ * 32); \
    A0 = ap_[0]; A1 = ap_[1]; A2 = ap_[2]; A3 = ap_[3]; } while (0)

#define CVW(A0, A1, A2, A3, WB) do { \
    uint4v s_; \
    s_[0] = pk2(A0[0], A0[1]); s_[1] = pk2(A0[2], A0[3]); \
    s_[2] = pk2(A1[0], A1[1]); s_[3] = pk2(A1[2], A1[3]); \
    *(uint4v*)&(WB)[aw0] = s_; \
    s_[0] = pk2(A2[0], A2[1]); s_[1] = pk2(A2[2], A2[3]); \
    s_[2] = pk2(A3[0], A3[1]); s_[3] = pk2(A3[2], A3[3]); \
    *(uint4v*)&(WB)[aw1] = s_; } while (0)

#define FRAGS(AB, TT) do { \
    const int ko_ = ((TT) >> 1) * 64; \
    const int kb_ = (((TT) & 1) << 2) | fg; \
    for (int i_ = 0; i_ < 4; ++i_) { \
      bfv[i_] = *(const short8*)&b_lds[boff[i_] + ko_ + ((kb_ ^ bx[i_]) * 8)]; \
      af[i_] = *(const short8*)&(AB)[aoff[i_]]; \
    } } while (0)

#define MFMA16() do { \
    __builtin_amdgcn_s_setprio(1); \
    for (int mi_ = 0; mi_ < 4; ++mi_) \
      for (int ni_ = 0; ni_ < 4; ++ni_) \
        acc[mi_][ni_] = __builtin_amdgcn_mfma_f32_16x16x32_bf16(af[mi_], bfv[ni_], acc[mi_][ni_], 0, 0, 0); \
    __builtin_amdgcn_s_setprio(0); } while (0)

#define BARRIER() do { \
    asm volatile("s_waitcnt lgkmcnt(0)" ::: "memory"); \
    __builtin_amdgcn_s_barrier(); } while (0)

// ============ proj: K/V projection, B-panel resident, 8 M-tiles/block =======
__global__ __launch_bounds__(256) void proj_kernel(
    const float* __restrict__ Kin, const float* __restrict__ Vin,
    const short* __restrict__ Wt,
    const float* __restrict__ bK, const float* __restrict__ bV,
    short* __restrict__ kp, short* __restrict__ vp)
{
  const int phys = blockIdx.x;
  const int log_ = (phys & 7) * 32 + (phys >> 3);   // 256 = 8*32 bijective
  const int z = log_ >> 7;
  const int col0 = ((log_ >> 5) & 3) * 128;
  const int m0 = (log_ & 31) * 1024;                // 8 M-tiles of 128

  const float* X = z ? Vin : Kin;
  const short* Bsrc = Wt + (size_t)z * 512 * 512;
  const float* bias = z ? bV : bK;
  short* dst = z ? vp : kp;

  __shared__ short b_lds[128 * 512];     // 128 KB, resident all block
  __shared__ short a_lds[2][128 * 32];   // 16 KB dbuf

  const int tid = threadIdx.x;
  const int lane = tid & 63, wv = tid >> 6;
  const int wr = wv >> 1, wc = wv & 1;
  const int fr = lane & 15, fg = lane >> 4;

  // B panel load, once: one gl_lds16 wave-op fills one 512-elem row.
  // dest = row*512 + lane*8 (HW: uniform base + lane*16B); source slot pre-XOR'd.
#pragma unroll
  for (int it = 0; it < 32; ++it) {
    const int row = wv * 32 + it;
    const int srck = (lane >> 3) * 64 + (((lane & 7) ^ (row & 7)) * 8);
    gl_lds16(Bsrc + (size_t)(col0 + row) * 512 + srck, &b_lds[row * 512 + lane * 8]);
  }

  const int ar = tid >> 1, ah = tid & 1;
  const int am = (ar & 3) ^ ((ar >> 2) & 3);
  const int aw0 = ar * 32 + (((2 * ah) ^ am) & 3) * 8;
  const int aw1 = ar * 32 + (((2 * ah + 1) ^ am) & 3) * 8;
  const float* abase = X + (size_t)m0 * 512 + ah * 16;

  int aoff[4], boff[4], bx[4];
#pragma unroll
  for (int i = 0; i < 4; ++i) {
    const int ra = wr * 64 + i * 16 + fr;
    aoff[i] = ra * 32 + (((fg ^ (ra & 3) ^ ((ra >> 2) & 3)) & 3) * 8);
    const int rb = wc * 64 + i * 16 + fr;
    boff[i] = rb * 512;
    bx[i] = rb & 7;
  }

  f32x4 acc[4][4];
#pragma unroll
  for (int i = 0; i < 4; ++i)
#pragma unroll
    for (int j = 0; j < 4; ++j) acc[i][j] = (f32x4){0.f, 0.f, 0.f, 0.f};

  f32x4 pe0, pe1, pe2, pe3, po0, po1, po2, po3;
  short8 af[4], bfv[4];
  const int NSTEP = 128;                 // 8 M-tiles x 16 k-steps

  LDA(0, pe0, pe1, pe2, pe3);
  LDA(1, po0, po1, po2, po3);
  CVW(pe0, pe1, pe2, pe3, a_lds[0]);
  asm volatile("s_waitcnt vmcnt(0) lgkmcnt(0)" ::: "memory");
  __builtin_amdgcn_s_barrier();

  for (int s = 0; s < NSTEP; s += 2) {
    { // even: read buf0, issue A(s+2)->pe, cvt po(A(s+1))->buf1
      FRAGS(a_lds[0], s & 15);
      if (s + 2 < NSTEP) LDA(s + 2, pe0, pe1, pe2, pe3);
      MFMA16();
      CVW(po0, po1, po2, po3, a_lds[1]);
      BARRIER();
    }
    { // odd: read buf1, issue A(s+3)->po, cvt pe(A(s+2))->buf0, epilogue at tile end
      const int so = s + 1;
      FRAGS(a_lds[1], so & 15);
      if (so + 2 < NSTEP) LDA(so + 2, po0, po1, po2, po3);
      MFMA16();
      if (so + 1 < NSTEP) CVW(pe0, pe1, pe2, pe3, a_lds[0]);
      if ((so & 15) == 15) {
        const int mt = so >> 4;
        for (int ni = 0; ni < 4; ++ni) {
          const int gc = col0 + wc * 64 + ni * 16 + fr;
          const float bv = bias[gc];
          for (int mi = 0; mi < 4; ++mi)
            for (int r = 0; r < 4; ++r) {
              const int gr = m0 + mt * 128 + wr * 64 + mi * 16 + fg * 4 + r;
              dst[(size_t)gr * 512 + gc] = f2bf(acc[mi][ni][r] + bv);
            }
        }
        for (int i = 0; i < 4; ++i)
          for (int j = 0; j < 4; ++j) acc[i][j] = (f32x4){0.f, 0.f, 0.f, 0.f};
      }
      BARRIER();
    }
  }
}

// ---------------- LN + ktv accumulation (unchanged) -------------------------
#define SC 256
#define TP 264

__global__ __launch_bounds__(256) void ktv_kernel(
    const short* __restrict__ kp, const short* __restrict__ vp,
    const float* __restrict__ pos,
    const float* __restrict__ lnwK, const float* __restrict__ lnbK,
    const float* __restrict__ lnwV, const float* __restrict__ lnbV,
    float* __restrict__ ktv)
{
  const int nh = blockIdx.y;
  const int n = nh >> 4, h = nh & 15;
  const int s0 = blockIdx.x * SC;
  const int tid = threadIdx.x;

  __shared__ short klds[48 * TP];
  __shared__ short vlds[48 * TP];
  __shared__ float lw[2][32], lb[2][32];

  if (tid < 32) {
    lw[0][tid] = lnwK[h * 32 + tid]; lb[0][tid] = lnbK[h * 32 + tid];
    lw[1][tid] = lnwV[h * 32 + tid]; lb[1][tid] = lnbV[h * 32 + tid];
  }
  __syncthreads();

  const size_t rowix = (size_t)n * 8192 + (s0 + tid);
  {
    const short8* src = (const short8*)(kp + rowix * 512 + h * 32);
    short8 r0 = src[0], r1 = src[1], r2 = src[2], r3 = src[3];
    float x[32];
#pragma unroll
    for (int i = 0; i < 8; ++i) { x[i] = bf2f(r0[i]); x[8+i] = bf2f(r1[i]); x[16+i] = bf2f(r2[i]); x[24+i] = bf2f(r3[i]); }
    float mu = 0.f;
#pragma unroll
    for (int i = 0; i < 32; ++i) mu += x[i];
    mu *= (1.f / 32.f);
    float var = 0.f;
#pragma unroll
    for (int i = 0; i < 32; ++i) { float d = x[i] - mu; var += d * d; }
    var *= (1.f / 32.f);
    const float rstd = rsqrtf(var + 1e-5f);
#pragma unroll
    for (int d = 0; d < 32; ++d)
      klds[d * TP + tid] = f2bf((x[d] - mu) * rstd * lw[0][d] + lb[0][d]);
  }
  {
    const short8* src = (const short8*)(vp + rowix * 512 + h * 32);
    short8 r0 = src[0], r1 = src[1], r2 = src[2], r3 = src[3];
    float x[32];
#pragma unroll
    for (int i = 0; i < 8; ++i) { x[i] = bf2f(r0[i]); x[8+i] = bf2f(r1[i]); x[16+i] = bf2f(r2[i]); x[24+i] = bf2f(r3[i]); }
    float mu = 0.f;
#pragma unroll
    for (int i = 0; i < 32; ++i) mu += x[i];
    mu *= (1.f / 32.f);
    float var = 0.f;
#pragma unroll
    for (int i = 0; i < 32; ++i) { float d = x[i] - mu; var += d * d; }
    var *= (1.f / 32.f);
    const float rstd = rsqrtf(var + 1e-5f);
#pragma unroll
    for (int d = 0; d < 32; ++d)
      vlds[d * TP + tid] = f2bf((x[d] - mu) * rstd * lw[1][d] + lb[1][d]);
  }
  {
    const short p0 = f2bf(pos[rowix * 2]);
    const short p1 = f2bf(pos[rowix * 2 + 1]);
    klds[32 * TP + tid] = p0; klds[33 * TP + tid] = p1;
    vlds[32 * TP + tid] = p0; vlds[33 * TP + tid] = p1;
  }
  __syncthreads();

  const int wv = tid >> 6, lane = tid & 63;
  if (wv < 3) {
    const int fr = lane & 15, fg = lane >> 4;
    f32x4 acc[3];
#pragma unroll
    for (int i = 0; i < 3; ++i) acc[i] = (f32x4){0.f, 0.f, 0.f, 0.f};
    for (int kk = 0; kk < SC; kk += 32) {
      short8 a = *(const short8*)&klds[(wv * 16 + fr) * TP + kk + fg * 8];
#pragma unroll
      for (int ni = 0; ni < 3; ++ni) {
        short8 b = *(const short8*)&vlds[(ni * 16 + fr) * TP + kk + fg * 8];
        acc[ni] = __builtin_amdgcn_mfma_f32_16x16x32_bf16(a, b, acc[ni], 0, 0, 0);
      }
    }
#pragma unroll
    for (int ni = 0; ni < 3; ++ni) {
      const int ei = ni * 16 + fr;
      if (ei < 34) {
        const int er = (ei < 32) ? ei + 2 : ei - 32;
#pragma unroll
        for (int r = 0; r < 4; ++r) {
          const int di = wv * 16 + fg * 4 + r;
          if (di < 34) {
            const int dr = (di < 32) ? di + 2 : di - 32;
            atomicAdd(&ktv[((size_t)nh * 34 + dr) * 34 + er], acc[ni][r]);
          }
        }
      }
    }
  }
}

// ---- S-build (regridded 64x4): St[n][o][m] fp32 + Pp3 accumulators ---------
__global__ __launch_bounds__(256) void sbuild_kernel(
    const float* __restrict__ ktv, const float* __restrict__ fcW,
    const float* __restrict__ bQ, float* __restrict__ St, float* __restrict__ Pp3)
{
  const int nh = blockIdx.x;
  const int n = nh >> 4, h = nh & 15;
  const int jq = blockIdx.y;
  __shared__ float g[34 * 34];
  __shared__ float bq8[8];
  for (int i = threadIdx.x; i < 34 * 34; i += 256)
    g[i] = ktv[(size_t)nh * 34 * 34 + i] * (1.f / 8192.f);
  if (threadIdx.x < 8) bq8[threadIdx.x] = bQ[h * 32 + jq * 8 + threadIdx.x];
  __syncthreads();

  for (int o = threadIdx.x; o < 512; o += 256) {
    float wcol[34];
#pragma unroll
    for (int e = 0; e < 34; ++e) wcol[e] = fcW[(size_t)o * 544 + h * 34 + e];
    float rv = 0.f;
    float* srow = St + ((size_t)n * 512 + o) * 512 + h * 32 + jq * 8;
#pragma unroll
    for (int jj = 0; jj < 8; ++jj) {
      const int j = jq * 8 + jj;
      float s = 0.f;
#pragma unroll
      for (int e = 0; e < 34; ++e) s += g[(j + 2) * 34 + e] * wcol[e];
      srow[jj] = s;
      rv += bq8[jj] * s;
    }
    atomicAdd(&Pp3[((size_t)n * 3 + 2) * 512 + o], rv);
    if (jq == 0) {
      float p0 = 0.f, p1 = 0.f;
#pragma unroll
      for (int e = 0; e < 34; ++e) { p0 += g[e] * wcol[e]; p1 += g[34 + e] * wcol[e]; }
      atomicAdd(&Pp3[((size_t)n * 3 + 0) * 512 + o], p0);
      atomicAdd(&Pp3[((size_t)n * 3 + 1) * 512 + o], p1);
    }
  }
}

// ---- C-build: Ct[n][o][k] = sum_m St[n][o][m] * WQ[k][m], bf16 out ---------
__global__ __launch_bounds__(256) void cbuild_kernel(
    const float* __restrict__ St, const float* __restrict__ WQ,
    short* __restrict__ Ct)
{
  const int n = blockIdx.z;
  const int row0 = blockIdx.y * 128;   // o
  const int col0 = blockIdx.x * 128;   // k
  const float* A = St + (size_t)n * 512 * 512;
  const float* B = WQ;

  __shared__ short a_lds[128 * 32];
  __shared__ short b_lds2[128 * 32];

  const int tid = threadIdx.x;
  const int lane = tid & 63, wv = tid >> 6;
  const int wr = wv >> 1, wc = wv & 1;
  const int fr = lane & 15, fg = lane >> 4;
  const int ar = tid >> 1, ak = (tid & 1) * 16;

  f32x4 acc[4][4];
#pragma unroll
  for (int i = 0; i < 4; ++i)
#pragma unroll
    for (int j = 0; j < 4; ++j) acc[i][j] = (f32x4){0.f, 0.f, 0.f, 0.f};

  for (int k0 = 0; k0 < 512; k0 += 32) {
    __syncthreads();
    {
      const f32x4* ap = (const f32x4*)(A + (size_t)(row0 + ar) * 512 + k0 + ak);
      f32x4 f0 = ap[0], f1 = ap[1], f2 = ap[2], f3 = ap[3];
      uint4v s0, s1;
      s0[0] = pk2(f0[0], f0[1]); s0[1] = pk2(f0[2], f0[3]);
      s0[2] = pk2(f1[0], f1[1]); s0[3] = pk2(f1[2], f1[3]);
      s1[0] = pk2(f2[0], f2[1]); s1[1] = pk2(f2[2], f2[3]);
      s1[2] = pk2(f3[0], f3[1]); s1[3] = pk2(f3[2], f3[3]);
      *(uint4v*)&a_lds[ar * 32 + ak] = s0;
      *(uint4v*)&a_lds[ar * 32 + ak + 8] = s1;
      const f32x4* bp = (const f32x4*)(B + (size_t)(col0 + ar) * 512 + k0 + ak);
      f32x4 g0 = bp[0], g1 = bp[1], g2 = bp[2], g3 = bp[3];
      s0[0] = pk2(g0[0], g0[1]); s0[1] = pk2(g0[2], g0[3]);
      s0[2] = pk2(g1[0], g1[1]); s0[3] = pk2(g1[2], g1[3]);
      s1[0] = pk2(g2[0], g2[1]); s1[1] = pk2(g2[2], g2[3]);
      s1[2] = pk2(g3[0], g3[1]); s1[3] = pk2(g3[2], g3[3]);
      *(uint4v*)&b_lds2[ar * 32 + ak] = s0;
      *(uint4v*)&b_lds2[ar * 32 + ak + 8] = s1;
    }
    __syncthreads();

    short8 af[4], bfr[4];
#pragma unroll
    for (int mi = 0; mi < 4; ++mi)
      af[mi] = *(const short8*)&a_lds[(wr * 64 + mi * 16 + fr) * 32 + fg * 8];
#pragma unroll
    for (int ni = 0; ni < 4; ++ni)
      bfr[ni] = *(const short8*)&b_lds2[(wc * 64 + ni * 16 + fr) * 32 + fg * 8];
#pragma unroll
    for (int mi = 0; mi < 4; ++mi)
#pragma unroll
      for (int ni = 0; ni < 4; ++ni)
        acc[mi][ni] = __builtin_amdgcn_mfma_f32_16x16x32_bf16(af[mi], bfr[ni], acc[mi][ni], 0, 0, 0);
  }

#pragma unroll
  for (int ni = 0; ni < 4; ++ni) {
    const int gc = col0 + wc * 64 + ni * 16 + fr;
#pragma unroll
    for (int mi = 0; mi < 4; ++mi)
#pragma unroll
      for (int r = 0; r < 4; ++r) {
        const int gr = row0 + wr * 64 + mi * 16 + fg * 4 + r;
        Ct[((size_t)n * 512 + gr) * 512 + gc] = f2bf(acc[mi][ni][r]);
      }
  }
}

// ============ fuse: out[n] = Q[n] @ Ct[n]^T + pos terms, B-panel resident ===
__global__ __launch_bounds__(256) void fuse_kernel(
    const float* __restrict__ Q, const short* __restrict__ Ct,
    const float* __restrict__ pos, const float* __restrict__ Pp3,
    const float* __restrict__ fcb, float* __restrict__ out)
{
  const int phys = blockIdx.x;
  const int log_ = (phys & 7) * 32 + (phys >> 3);   // 256 = 8*32
  const int n = log_ >> 6;
  const int col0 = ((log_ >> 4) & 3) * 128;
  const int m0 = (log_ & 15) * 512;                 // 4 M-tiles of 128

  const float* X = Q + (size_t)n * 8192 * 512;
  const short* Bsrc = Ct + (size_t)n * 512 * 512;
  float* dstf = out + (size_t)n * 8192 * 512;
  const float* posn = pos + (size_t)n * 8192 * 2;

  __shared__ short b_lds[128 * 512];
  __shared__ short a_lds[2][128 * 32];

  const int tid = threadIdx.x;
  const int lane = tid & 63, wv = tid >> 6;
  const int wr = wv >> 1, wc = wv & 1;
  const int fr = lane & 15, fg = lane >> 4;

#pragma unroll
  for (int it = 0; it < 32; ++it) {
    const int row = wv * 32 + it;
    const int srck = (lane >> 3) * 64 + (((lane & 7) ^ (row & 7)) * 8);
    gl_lds16(Bsrc + (size_t)(col0 + row) * 512 + srck, &b_lds[row * 512 + lane * 8]);
  }

  const int ar = tid >> 1, ah = tid & 1;
  const int am = (ar & 3) ^ ((ar >> 2) & 3);
  const int aw0 = ar * 32 + (((2 * ah) ^ am) & 3) * 8;
  const int aw1 = ar * 32 + (((2 * ah + 1) ^ am) & 3) * 8;
  const float* abase = X + (size_t)m0 * 512 + ah * 16;

  int aoff[4], boff[4], bx[4];
#pragma unroll
  for (int i = 0; i < 4; ++i) {
    const int ra = wr * 64 + i * 16 + fr;
    aoff[i] = ra * 32 + (((fg ^ (ra & 3) ^ ((ra >> 2) & 3)) & 3) * 8);
    const int rb = wc * 64 + i * 16 + fr;
    boff[i] = rb * 512;
    bx[i] = rb & 7;
  }

  float pp0[4], pp1[4], rv[4];
#pragma unroll
  for (int ni = 0; ni < 4; ++ni) {
    const int gc = col0 + wc * 64 + ni * 16 + fr;
    pp0[ni] = Pp3[((size_t)n * 3 + 0) * 512 + gc];
    pp1[ni] = Pp3[((size_t)n * 3 + 1) * 512 + gc];
    rv[ni]  = Pp3[((size_t)n * 3 + 2) * 512 + gc] + fcb[gc];
  }

  f32x4 acc[4][4];
#pragma unroll
  for (int i = 0; i < 4; ++i)
#pragma unroll
    for (int j = 0; j < 4; ++j) acc[i][j] = (f32x4){0.f, 0.f, 0.f, 0.f};

  f32x4 pe0, pe1, pe2, pe3, po0, po1, po2, po3;
  short8 af[4], bfv[4];
  const int NSTEP = 64;                  // 4 M-tiles x 16 k-steps

  LDA(0, pe0, pe1, pe2, pe3);
  LDA(1, po0, po1, po2, po3);
  CVW(pe0, pe1, pe2, pe3, a_lds[0]);
  asm volatile("s_waitcnt vmcnt(0) lgkmcnt(0)" ::: "memory");
  __builtin_amdgcn_s_barrier();

  for (int s = 0; s < NSTEP; s += 2) {
    {
      FRAGS(a_lds[0], s & 15);
      if (s + 2 < NSTEP) LDA(s + 2, pe0, pe1, pe2, pe3);
      MFMA16();
      CVW(po0, po1, po2, po3, a_lds[1]);
      BARRIER();
    }
    {
      const int so = s + 1;
      FRAGS(a_lds[1], so & 15);
      if (so + 2 < NSTEP) LDA(so + 2, po0, po1, po2, po3);
      MFMA16();
      if (so + 1 < NSTEP) CVW(pe0, pe1, pe2, pe3, a_lds[0]);
      if ((so & 15) == 15) {
        const int mt = so >> 4;
        for (int mi = 0; mi < 4; ++mi)
          for (int r = 0; r < 4; ++r) {
            const int gr = m0 + mt * 128 + wr * 64 + mi * 16 + fg * 4 + r;
            const float q0 = posn[(size_t)gr * 2];
            const float q1 = posn[(size_t)gr * 2 + 1];
            for (int ni = 0; ni < 4; ++ni) {
              const int gc = col0 + wc * 64 + ni * 16 + fr;
              dstf[(size_t)gr * 512 + gc] =
                  acc[mi][ni][r] + pp0[ni] * q0 + pp1[ni] * q1 + rv[ni];
            }
          }
        for (int i = 0; i < 4; ++i)
          for (int j = 0; j < 4; ++j) acc[i][j] = (f32x4){0.f, 0.f, 0.f, 0.f};
      }
      BARRIER();
    }
  }
}

// ---------------------------------------------------------------------------
extern "C" void kernel_launch(void* const* d_in, const int* in_sizes, int n_in,
                              void* d_out, int out_size, void* d_ws, size_t ws_size,
                              hipStream_t stream) {
  const float* Q    = (const float*)d_in[0];
  const float* Kin  = (const float*)d_in[1];
  const float* Vin  = (const float*)d_in[2];
  const float* pos  = (const float*)d_in[3];
  const float* WQ   = (const float*)d_in[4];
  const float* WK   = (const float*)d_in[5];
  const float* WV   = (const float*)d_in[6];
  const float* bQ   = (const float*)d_in[7];
  const float* bK   = (const float*)d_in[8];
  const float* bV   = (const float*)d_in[9];
  const float* lnwK = (const float*)d_in[10];
  const float* lnbK = (const float*)d_in[11];
  const float* lnwV = (const float*)d_in[12];
  const float* lnbV = (const float*)d_in[13];
  const float* fcW  = (const float*)d_in[14];
  const float* fcb  = (const float*)d_in[15];

  char* ws = (char*)d_ws;
  const size_t KP_B  = (size_t)4 * 8192 * 512 * 2;   // 33,554,432
  const size_t KTV_B = (size_t)64 * 34 * 34 * 4;     //    295,936
  const size_t ST_B  = (size_t)4 * 512 * 512 * 4;    //  4,194,304
  const size_t CT_B  = (size_t)4 * 512 * 512 * 2;    //  2,097,152
  const size_t WT_B  = (size_t)2 * 512 * 512 * 2;    //  1,048,576
  const size_t PP_B  = (size_t)4 * 3 * 512 * 4;      //     24,576
  short* kp  = (short*)ws;
  short* vp  = (short*)(ws + KP_B);
  float* ktv = (float*)(ws + 2 * KP_B);
  float* St  = (float*)(ws + 2 * KP_B + KTV_B);
  short* Ct  = (short*)(ws + 2 * KP_B + KTV_B + ST_B);
  short* Wt  = (short*)(ws + 2 * KP_B + KTV_B + ST_B + CT_B);
  float* Pp3 = (float*)(ws + 2 * KP_B + KTV_B + ST_B + CT_B + WT_B);

  (void)hipMemsetAsync(ktv, 0, KTV_B, stream);
  (void)hipMemsetAsync(Pp3, 0, PP_B, stream);
  hipLaunchKernelGGL(wt_kernel, dim3(8, 8, 2), dim3(256), 0, stream, WK, WV, Wt);
  hipLaunchKernelGGL(proj_kernel, dim3(256), dim3(256), 0, stream,
                     Kin, Vin, Wt, bK, bV, kp, vp);
  hipLaunchKernelGGL(ktv_kernel, dim3(32, 64), dim3(256), 0, stream,
                     kp, vp, pos, lnwK, lnbK, lnwV, lnbV, ktv);
  hipLaunchKernelGGL(sbuild_kernel, dim3(64, 4), dim3(256), 0, stream,
                     ktv, fcW, bQ, St, Pp3);
  hipLaunchKernelGGL(cbuild_kernel, dim3(4, 4, 4), dim3(256), 0, stream,
                     St, WQ, Ct);
  hipLaunchKernelGGL(fuse_kernel, dim3(256), dim3(256), 0, stream,
                     Q, Ct, pos, Pp3, fcb, (float*)d_out);
}